// Round 3
// baseline (7308.405 us; speedup 1.0000x reference)
//
#include <hip/hip_runtime.h>
#include <hip/hip_fp16.h>

#define NN 100000
#define NE 1600000
#define HD 128
#define HD2 256

// binned scatter params
#define NBK 512
#define RPB 196      // rows per bucket; 512*196 = 100352 >= NN
#define CH  4096     // edges per binscatter block

typedef unsigned int u32;
typedef unsigned short u16;
typedef _Float16 half8 __attribute__((ext_vector_type(8)));
typedef float floatx4 __attribute__((ext_vector_type(4)));

static inline int cdiv(int a, int b){ return (a + b - 1) / b; }

// ---- split-fp16 packing: x ~= h + l * 2^-12, l pre-scaled by 4096 ----
__device__ __forceinline__ u32 split_pack(float v){
  __half h;
  if(fabsf(v) < 6.103515625e-05f) h = __ushort_as_half((u16)0);
  else h = __float2half_rn(v);
  float hf = __half2float(h);
  __half l = __float2half_rn((v - hf) * 4096.0f);
  return (u32)__half_as_ushort(h) | ((u32)__half_as_ushort(l) << 16);
}

// ---------------- utility kernels ----------------
__global__ void k_zero_int(int* __restrict__ p, int n){
  int i = blockIdx.x * 256 + threadIdx.x;
  if(i < n) p[i] = 0;
}

__global__ void k_zero_f(float* __restrict__ p, int n){
  int i = blockIdx.x * 256 + threadIdx.x;
  if(i < n) p[i] = 0.f;
}

// ---------------- batched CSR build (blockIdx.y = adjacency), packed (col,val) ----------------
__global__ void k_hist2(const int* __restrict__ r0, const int* __restrict__ r1,
                        int* __restrict__ cnt){
  int e = blockIdx.x * 256 + threadIdx.x;
  if(e < NE){
    const int* rows = blockIdx.y ? r1 : r0;
    atomicAdd(&cnt[blockIdx.y * NN + rows[e]], 1);
  }
}

__global__ void k_scan1b(const int* __restrict__ cnt, int* __restrict__ p0,
                         int* __restrict__ p1, int* __restrict__ sums, int n){
  __shared__ int sh[256];
  int z = blockIdx.y;
  const int* c = cnt + z * n;
  int* part = z ? p1 : p0;
  int* sm = sums + z * 128;
  int tid = threadIdx.x;
  int base = blockIdx.x * 1024 + tid * 4;
  int v0 = (base + 0 < n) ? c[base + 0] : 0;
  int v1 = (base + 1 < n) ? c[base + 1] : 0;
  int v2 = (base + 2 < n) ? c[base + 2] : 0;
  int v3 = (base + 3 < n) ? c[base + 3] : 0;
  int s = v0 + v1 + v2 + v3;
  sh[tid] = s;
  __syncthreads();
  for(int d = 1; d < 256; d <<= 1){
    int t = (tid >= d) ? sh[tid - d] : 0;
    __syncthreads();
    sh[tid] += t;
    __syncthreads();
  }
  int excl = sh[tid] - s;
  if(tid == 255) sm[blockIdx.x] = sh[255];
  if(base + 0 < n) part[base + 0] = excl;
  if(base + 1 < n) part[base + 1] = excl + v0;
  if(base + 2 < n) part[base + 2] = excl + v0 + v1;
  if(base + 3 < n) part[base + 3] = excl + v0 + v1 + v2;
}

__global__ void k_scan2b(int* __restrict__ sums, int nb){
  __shared__ int sh[128];
  int* s = sums + blockIdx.x * 128;
  int tid = threadIdx.x;
  int v = (tid < nb) ? s[tid] : 0;
  sh[tid] = v;
  __syncthreads();
  for(int d = 1; d < 128; d <<= 1){
    int t = (tid >= d) ? sh[tid - d] : 0;
    __syncthreads();
    sh[tid] += t;
    __syncthreads();
  }
  if(tid < nb) s[tid] = sh[tid] - v;
}

__global__ void k_scan3b(int* __restrict__ r0, int* __restrict__ r1,
                         int* __restrict__ cursor, const int* __restrict__ sums, int n){
  int z = blockIdx.y;
  int* rowptr = z ? r1 : r0;
  int* cur = cursor + z * n;
  int off = sums[z * 128 + blockIdx.x];
  int tid = threadIdx.x;
  int base = blockIdx.x * 1024 + tid * 4;
  #pragma unroll
  for(int j = 0; j < 4; j++){
    int idx = base + j;
    if(idx < n){ int r = rowptr[idx] + off; rowptr[idx] = r; cur[idx] = r; }
  }
  if(blockIdx.x == 0 && tid == 0) rowptr[n] = NE;
}

// bucket cursor init: bucket b starts at rowptr[min(b*RPB, NN)]
__global__ void k_init_bcur(const int* __restrict__ c1ptr, const int* __restrict__ c2ptr,
                            int* __restrict__ cursor){
  int b = blockIdx.x * 256 + threadIdx.x;
  int z = blockIdx.y;
  if(b < NBK){
    const int* rp = z ? c2ptr : c1ptr;
    int r = b * RPB; if(r > NN) r = NN;
    cursor[z * NN + b] = rp[r];
  }
}

// pass B: LDS-binned scatter into bucket-contiguous staging (burst writes)
__global__ void k_binscatter(const int* __restrict__ r0a, const int* __restrict__ c0a,
                             const float* __restrict__ v0a,
                             const int* __restrict__ r1a, const int* __restrict__ c1a,
                             const float* __restrict__ v1a,
                             int* __restrict__ bcur,
                             u32* __restrict__ sr0, uint2* __restrict__ sv0,
                             u32* __restrict__ sr1, uint2* __restrict__ sv1){
  __shared__ int cnt[NBK];
  __shared__ int bstart[NBK];
  __shared__ int gbase[NBK];
  __shared__ int sh[256];
  __shared__ u32 srow[CH];
  __shared__ uint2 scvs[CH];
  int z = blockIdx.y;
  const int* rows = z ? r1a : r0a;
  const int* cols = z ? c1a : c0a;
  const float* vals = z ? v1a : v0a;
  int* cur = bcur + z * NN;
  u32* osr = z ? sr1 : sr0;
  uint2* osv = z ? sv1 : sv0;
  int t = threadIdx.x;
  for(int i = t; i < NBK; i += 256) cnt[i] = 0;
  __syncthreads();
  int e0 = blockIdx.x * CH;
  int total = NE - e0; if(total > CH) total = CH;
  int r_[16], c_[16], b_[16], k_[16]; float v_[16];
  #pragma unroll
  for(int k = 0; k < 16; k++){
    int e = e0 + t + k * 256;
    b_[k] = -1;
    if(e < NE){
      r_[k] = rows[e]; c_[k] = cols[e]; v_[k] = vals[e];
      b_[k] = r_[k] / RPB;
      k_[k] = atomicAdd(&cnt[b_[k]], 1);
    }
  }
  __syncthreads();
  // exclusive scan of cnt[512] with 256 threads (2 elems/thread)
  int v0 = cnt[2 * t], v1 = cnt[2 * t + 1];
  int s2 = v0 + v1;
  sh[t] = s2;
  __syncthreads();
  for(int d = 1; d < 256; d <<= 1){
    int tv = (t >= d) ? sh[t - d] : 0;
    __syncthreads();
    sh[t] += tv;
    __syncthreads();
  }
  int excl = sh[t] - s2;
  bstart[2 * t] = excl;
  bstart[2 * t + 1] = excl + v0;
  __syncthreads();
  // stage into LDS sorted-by-bucket
  #pragma unroll
  for(int k = 0; k < 16; k++){
    if(b_[k] >= 0){
      int slot = bstart[b_[k]] + k_[k];
      srow[slot] = (u32)r_[k];
      scvs[slot] = make_uint2((u32)c_[k], __float_as_uint(v_[k]));
    }
  }
  // reserve global space per bucket (one atomic per non-empty bucket)
  for(int b = t; b < NBK; b += 256){
    int c = cnt[b];
    if(c > 0) gbase[b] = atomicAdd(&cur[b], c);
  }
  __syncthreads();
  // burst write-out: consecutive i -> same bucket -> contiguous dest
  for(int i = t; i < total; i += 256){
    u32 r = srow[i];
    int b = (int)r / RPB;
    int dest = gbase[b] + (i - bstart[b]);
    osr[dest] = r;
    osv[dest] = scvs[i];
  }
}

// pass C: per-bucket placement into final CSR order (dest region ~25KB, L2-hot)
__global__ void k_bucket_place(const int* __restrict__ c1ptr, const int* __restrict__ c2ptr,
                               const u32* __restrict__ sr0, const uint2* __restrict__ sv0,
                               const u32* __restrict__ sr1, const uint2* __restrict__ sv1,
                               uint2* __restrict__ e0, uint2* __restrict__ e1){
  __shared__ int cur[RPB];
  int z = blockIdx.y;
  const int* rp = z ? c2ptr : c1ptr;
  const u32* sr = z ? sr1 : sr0;
  const uint2* sv = z ? sv1 : sv0;
  uint2* ecv = z ? e1 : e0;
  int b = blockIdx.x;
  int r0 = b * RPB;
  if(r0 >= NN) return;
  int rend = r0 + RPB; if(rend > NN) rend = NN;
  int t = threadIdx.x;
  for(int r = t; r < rend - r0; r += 256) cur[r] = rp[r0 + r];
  __syncthreads();
  int s = rp[r0], e = rp[rend];
  for(int i = s + t; i < e; i += 256){
    u32 r = sr[i];
    uint2 cv = sv[i];
    int p = atomicAdd(&cur[r - r0], 1);
    ecv[p] = cv;
  }
}

// weight pre-split into separate h/l planes: W is [K][N] row-major fp32;
// planes are [N][K] u16 (transposed), linear.
__global__ void k_splitw(const float* __restrict__ W, u16* __restrict__ oh,
                         u16* __restrict__ ol, int K, int N, int total){
  int idx = blockIdx.x * 256 + threadIdx.x;
  if(idx < total){
    int n = idx / K, k = idx - n * K;
    u32 p = split_pack(W[(size_t)k * N + n]);
    oh[idx] = (u16)(p & 0xffffu);
    ol[idx] = (u16)(p >> 16);
  }
}

// ---------------- SpMM: one wave per node; relu (+ optional l2norm); h/l plane output ----
template<bool NORM>
__global__ void k_spmm(const int* __restrict__ rowptr, const uint2* __restrict__ ecv,
                       const float* __restrict__ X, u16* __restrict__ Xh,
                       u16* __restrict__ Xl){
  int node = (blockIdx.x << 2) + (threadIdx.x >> 6);
  int lane = threadIdx.x & 63;
  if(node >= NN) return;
  int s = rowptr[node], e = rowptr[node + 1];
  float ax = 0.f, ay = 0.f, bx = 0.f, by = 0.f;
  int i = s;
  for(; i + 15 < e; i += 16){
    uint2 ee[16]; float2 xx[16];
    #pragma unroll
    for(int j = 0; j < 16; j++) ee[j] = ecv[i + j];
    #pragma unroll
    for(int j = 0; j < 16; j++) xx[j] = *(const float2*)(X + (size_t)ee[j].x * HD + lane * 2);
    #pragma unroll
    for(int j = 0; j < 16; j += 4){
      ax += __uint_as_float(ee[j].y)   * xx[j].x   + __uint_as_float(ee[j+1].y) * xx[j+1].x;
      ay += __uint_as_float(ee[j].y)   * xx[j].y   + __uint_as_float(ee[j+1].y) * xx[j+1].y;
      bx += __uint_as_float(ee[j+2].y) * xx[j+2].x + __uint_as_float(ee[j+3].y) * xx[j+3].x;
      by += __uint_as_float(ee[j+2].y) * xx[j+2].y + __uint_as_float(ee[j+3].y) * xx[j+3].y;
    }
  }
  for(; i + 3 < e; i += 4){
    uint2 f0 = ecv[i], f1 = ecv[i+1], f2 = ecv[i+2], f3 = ecv[i+3];
    float2 x0 = *(const float2*)(X + (size_t)f0.x * HD + lane * 2);
    float2 x1 = *(const float2*)(X + (size_t)f1.x * HD + lane * 2);
    float2 x2 = *(const float2*)(X + (size_t)f2.x * HD + lane * 2);
    float2 x3 = *(const float2*)(X + (size_t)f3.x * HD + lane * 2);
    ax += __uint_as_float(f0.y) * x0.x + __uint_as_float(f1.y) * x1.x;
    ay += __uint_as_float(f0.y) * x0.y + __uint_as_float(f1.y) * x1.y;
    bx += __uint_as_float(f2.y) * x2.x + __uint_as_float(f3.y) * x3.x;
    by += __uint_as_float(f2.y) * x2.y + __uint_as_float(f3.y) * x3.y;
  }
  for(; i < e; i++){
    uint2 f0 = ecv[i];
    float2 xv = *(const float2*)(X + (size_t)f0.x * HD + lane * 2);
    ax += __uint_as_float(f0.y) * xv.x;
    ay += __uint_as_float(f0.y) * xv.y;
  }
  ax += bx; ay += by;
  ax = fmaxf(ax, 0.f);
  ay = fmaxf(ay, 0.f);
  if(NORM){
    float ss = ax * ax + ay * ay;
    #pragma unroll
    for(int o = 32; o >= 1; o >>= 1) ss += __shfl_xor(ss, o, 64);
    float scale = 1.f / fmaxf(sqrtf(ss), 1e-12f);
    ax *= scale; ay *= scale;
  }
  u32 p0 = split_pack(ax), p1 = split_pack(ay);
  *(u32*)(Xh + (size_t)node * HD + lane * 2) = (p0 & 0xffffu) | ((p1 & 0xffffu) << 16);
  *(u32*)(Xl + (size_t)node * HD + lane * 2) = (p0 >> 16) | (p1 & 0xffff0000u);
}

// ---------------- split-fp16 MFMA GEMM (r6-proven pipeline; plane staging, no unpack) ----
// A: u16 planes Ah/Al [M][K]; B: u16 planes [N][K] (pre-transposed).
// Staging is a pure bit-copy: global uint4 -> LDS uint4 (no VALU unpack).
// MODE 0: Yout = A@B (fp32). MODE 1: H planes = split(relu(A@B+bias)).
// MODE 2: score[m] += sum_n relu(A@B+bias)[m][n]*m3[n].
// MODE 3: fused — blockIdx.y==0: mode0 with B -> Yout [M][HD];
//                 blockIdx.y in {1,2}: mode1 col-tile with B1 -> H planes [M][HD2].
template<int MODE>
__launch_bounds__(256, 2)
__global__ void k_mfma_gemm(const u16* __restrict__ Ah, const u16* __restrict__ Al,
                            const u16* __restrict__ Bh, const u16* __restrict__ Bl,
                            const u16* __restrict__ B1h, const u16* __restrict__ B1l,
                            const float* __restrict__ bias, float* __restrict__ Yout,
                            u16* __restrict__ Hh, u16* __restrict__ Hl,
                            const float* __restrict__ m3, float* __restrict__ score,
                            int M, int K, int N){
  __shared__ u16 As_h[128 * 40], As_l[128 * 40];
  __shared__ u16 Bs_h[128 * 40], Bs_l[128 * 40];
  const int tid = threadIdx.x;
  const int lane = tid & 63, wid = tid >> 6;
  const int lm = lane & 15, lg = lane >> 4;
  const int mq = (wid & 1) * 64, nq = (wid >> 1) * 64;
  const int m0 = blockIdx.x * 128;
  int n0 = blockIdx.y * 128;
  const u16* Bth = Bh; const u16* Btl = Bl;
  bool m0path = true;
  if(MODE == 3){
    m0path = (blockIdx.y == 0);
    if(m0path){ n0 = 0; }
    else      { n0 = (blockIdx.y - 1) * 128; Bth = B1h; Btl = B1l; }
  }

  floatx4 accA[4][4], accB[4][4];
  #pragma unroll
  for(int i = 0; i < 4; i++)
    #pragma unroll
    for(int j = 0; j < 4; j++){
      accA[i][j] = (floatx4){0.f, 0.f, 0.f, 0.f};
      accB[i][j] = (floatx4){0.f, 0.f, 0.f, 0.f};
    }

  for(int k0 = 0; k0 < K; k0 += 32){
    // stage 128x32 u16 per plane: 512 granules of 16B; 2 per thread per plane
    uint4 avh[2], avl[2], bvh[2], bvl[2];
    #pragma unroll
    for(int j = 0; j < 2; j++){
      int li = tid + j * 256;
      int row = li >> 2, kc = (li & 3) * 8;
      int ar = m0 + row; if(ar >= M) ar = M - 1;
      size_t ao = (size_t)ar * K + k0 + kc;
      size_t bo = (size_t)(n0 + row) * K + k0 + kc;
      avh[j] = *(const uint4*)(Ah + ao);
      avl[j] = *(const uint4*)(Al + ao);
      bvh[j] = *(const uint4*)(Bth + bo);
      bvl[j] = *(const uint4*)(Btl + bo);
    }
    if(k0) __syncthreads();
    #pragma unroll
    for(int j = 0; j < 2; j++){
      int li = tid + j * 256;
      int row = li >> 2, kc = (li & 3) * 8;
      int base = row * 40 + kc;        // byte = row*80 + kc*2, always 16B-aligned
      *(uint4*)&As_h[base] = avh[j];
      *(uint4*)&As_l[base] = avl[j];
      *(uint4*)&Bs_h[base] = bvh[j];
      *(uint4*)&Bs_l[base] = bvl[j];
    }
    __syncthreads();

    half8 fa_h[4], fa_l[4], fb_h[4], fb_l[4];
    #pragma unroll
    for(int s = 0; s < 4; s++){
      int ra = (mq + s * 16 + lm) * 40 + lg * 8;
      fa_h[s] = *(const half8*)&As_h[ra];
      fa_l[s] = *(const half8*)&As_l[ra];
      int rb = (nq + s * 16 + lm) * 40 + lg * 8;
      fb_h[s] = *(const half8*)&Bs_h[rb];
      fb_l[s] = *(const half8*)&Bs_l[rb];
    }
    #pragma unroll
    for(int i = 0; i < 4; i++)
      #pragma unroll
      for(int j = 0; j < 4; j++){
        accA[i][j] = __builtin_amdgcn_mfma_f32_16x16x32_f16(fa_h[i], fb_h[j], accA[i][j], 0, 0, 0);
        accB[i][j] = __builtin_amdgcn_mfma_f32_16x16x32_f16(fa_h[i], fb_l[j], accB[i][j], 0, 0, 0);
        accB[i][j] = __builtin_amdgcn_mfma_f32_16x16x32_f16(fa_l[i], fb_h[j], accB[i][j], 0, 0, 0);
      }
  }

  const float inv4096 = 1.f / 4096.f;
  if(MODE == 0 || (MODE == 3 && m0path)){
    int ldy = (MODE == 3) ? HD : N;
    #pragma unroll
    for(int i = 0; i < 4; i++)
      #pragma unroll
      for(int r = 0; r < 4; r++){
        int m = m0 + mq + i * 16 + lg * 4 + r;
        if(m < M){
          #pragma unroll
          for(int j = 0; j < 4; j++){
            int c = n0 + nq + j * 16 + lm;
            Yout[(size_t)m * ldy + c] = accA[i][j][r] + accB[i][j][r] * inv4096;
          }
        }
      }
  } else if(MODE == 1 || MODE == 3){
    int ldh = (MODE == 3) ? HD2 : N;
    #pragma unroll
    for(int i = 0; i < 4; i++)
      #pragma unroll
      for(int r = 0; r < 4; r++){
        int m = m0 + mq + i * 16 + lg * 4 + r;
        if(m < M){
          #pragma unroll
          for(int j = 0; j < 4; j++){
            int c = n0 + nq + j * 16 + lm;
            float v = fmaxf(accA[i][j][r] + accB[i][j][r] * inv4096 + bias[c], 0.f);
            u32 p = split_pack(v);
            Hh[(size_t)m * ldh + c] = (u16)(p & 0xffffu);
            Hl[(size_t)m * ldh + c] = (u16)(p >> 16);
          }
        }
      }
  } else {
    #pragma unroll
    for(int i = 0; i < 4; i++)
      #pragma unroll
      for(int r = 0; r < 4; r++){
        float s = 0.f;
        #pragma unroll
        for(int j = 0; j < 4; j++){
          int c = n0 + nq + j * 16 + lm;
          float v = fmaxf(accA[i][j][r] + accB[i][j][r] * inv4096 + bias[c], 0.f);
          s = fmaf(v, m3[c], s);
        }
        s += __shfl_xor(s, 1, 64);
        s += __shfl_xor(s, 2, 64);
        s += __shfl_xor(s, 4, 64);
        s += __shfl_xor(s, 8, 64);
        int m = m0 + mq + i * 16 + lg * 4 + r;
        if(lm == 0 && m < M) atomicAdd(&score[m], s);
      }
  }
}

__global__ void k_final(const float* __restrict__ sc, const float* __restrict__ b3,
                        float* __restrict__ out){
  int i = blockIdx.x * 256 + threadIdx.x;
  if(i < NN){
    float b = 9.f * b3[0];
    out[i] = (sc[i] + b) * (sc[NN + i] + b);
  }
}

// ---------------- launcher ----------------
extern "C" void kernel_launch(void* const* d_in, const int* in_sizes, int n_in,
                              void* d_out, int out_size, void* d_ws, size_t ws_size,
                              hipStream_t stream){
  const int*   a1r = (const int*)d_in[0];
  const int*   a1c = (const int*)d_in[1];
  const float* a1v = (const float*)d_in[2];
  const int*   a2r = (const int*)d_in[3];
  const int*   a2c = (const int*)d_in[4];
  const float* a2v = (const float*)d_in[5];
  const float* w1  = (const float*)d_in[6];
  const float* w[8];
  for(int i = 0; i < 8; i++) w[i] = (const float*)d_in[7 + i];
  const float* m1 = (const float*)d_in[15];
  const float* b1 = (const float*)d_in[16];
  const float* m2 = (const float*)d_in[17];
  const float* b2 = (const float*)d_in[18];
  const float* m3 = (const float*)d_in[19];
  const float* b3 = (const float*)d_in[20];
  float* out = (float*)d_out;

  char* base = (char*)d_ws;
  size_t off = 0;
  auto alloc = [&](size_t bytes) -> char* {
    char* r = base + off;
    off += (bytes + 255) & ~(size_t)255;
    return r;
  };
  int*   c1ptr = (int*)  alloc((size_t)(NN + 1) * 4);
  int*   c2ptr = (int*)  alloc((size_t)(NN + 1) * 4);
  uint2* ecv1  = (uint2*)alloc((size_t)NE * 8);
  uint2* ecv2  = (uint2*)alloc((size_t)NE * 8);
  int*   cursor= (int*)  alloc((size_t)2 * NN * 4);
  int*   sums  = (int*)  alloc(1024);
  float* sc    = (float*)alloc((size_t)2 * NN * 4);
  u16*   wth[8]; u16* wtl[8];
  for(int i = 0; i < 8; i++){
    wth[i] = (u16*)alloc((size_t)HD * HD * 2);
    wtl[i] = (u16*)alloc((size_t)HD * HD * 2);
  }
  u16*   m1h = (u16*)alloc((size_t)HD2 * HD * 2);
  u16*   m1l = (u16*)alloc((size_t)HD2 * HD * 2);
  u16*   m2h = (u16*)alloc((size_t)HD2 * HD2 * 2);
  u16*   m2l = (u16*)alloc((size_t)HD2 * HD2 * 2);
  u16*   Xh  = (u16*)alloc((size_t)NN * HD * 2);
  u16*   Xl  = (u16*)alloc((size_t)NN * HD * 2);
  u16*   H1h = (u16*)alloc((size_t)NN * HD2 * 2);
  u16*   H1l = (u16*)alloc((size_t)NN * HD2 * 2);
  // fused01 tier needs dedicated y (fp32 [NN][HD]); else alias H1 and run r6 schedule
  size_t need_ded = off + (((size_t)NN * HD * 4 + 255) & ~(size_t)255);
  bool ded_y = (ws_size >= need_ded);
  float* y = ded_y ? (float*)alloc((size_t)NN * HD * 4) : (float*)H1h;

  // binned-scatter staging aliases H1h (dead during CSR build): 32MB < 51.2MB
  char* hb = (char*)H1h;
  uint2* sv1 = (uint2*)hb;
  u32*   sr1 = (u32*)(hb + (size_t)NE * 8);
  uint2* sv2 = (uint2*)(hb + (size_t)NE * 12);
  u32*   sr2 = (u32*)(hb + (size_t)NE * 20);

  // ---- batched CSR build (both adjacencies) ----
  hipLaunchKernelGGL(k_zero_int, dim3(cdiv(2 * NN, 256)), dim3(256), 0, stream, cursor, 2 * NN);
  hipLaunchKernelGGL(k_hist2, dim3(cdiv(NE, 256), 2), dim3(256), 0, stream, a1r, a2r, cursor);
  const int SCAN_BLOCKS = cdiv(NN, 1024);
  hipLaunchKernelGGL(k_scan1b, dim3(SCAN_BLOCKS, 2), dim3(256), 0, stream, cursor, c1ptr, c2ptr, sums, NN);
  hipLaunchKernelGGL(k_scan2b, dim3(2), dim3(128), 0, stream, sums, SCAN_BLOCKS);
  hipLaunchKernelGGL(k_scan3b, dim3(SCAN_BLOCKS, 2), dim3(256), 0, stream, c1ptr, c2ptr, cursor, sums, NN);
  hipLaunchKernelGGL(k_init_bcur, dim3(cdiv(NBK, 256), 2), dim3(256), 0, stream, c1ptr, c2ptr, cursor);
  hipLaunchKernelGGL(k_binscatter, dim3(cdiv(NE, CH), 2), dim3(256), 0, stream,
                     a1r, a1c, a1v, a2r, a2c, a2v, cursor, sr1, sv1, sr2, sv2);
  hipLaunchKernelGGL(k_bucket_place, dim3(NBK, 2), dim3(256), 0, stream,
                     c1ptr, c2ptr, sr1, sv1, sr2, sv2, ecv1, ecv2);

  auto splitw = [&](const float* W, u16* oh, u16* ol, int K, int N){
    int total = K * N;
    hipLaunchKernelGGL(k_splitw, dim3(cdiv(total, 256)), dim3(256), 0, stream, W, oh, ol, K, N, total);
  };
  for(int i = 0; i < 8; i++) splitw(w[i], wth[i], wtl[i], HD, HD);
  splitw(m1, m1h, m1l, HD, HD2);
  splitw(m2, m2h, m2l, HD2, HD2);
  hipLaunchKernelGGL(k_zero_f, dim3(cdiv(2 * NN, 256)), dim3(256), 0, stream, sc, 2 * NN);

  const int GX = cdiv(NN, 128);   // 782
  auto mode1 = [&](){
    hipLaunchKernelGGL((k_mfma_gemm<1>), dim3(GX, 2), dim3(256), 0, stream,
                       Xh, Xl, m1h, m1l, (const u16*)nullptr, (const u16*)nullptr,
                       b1, (float*)nullptr, H1h, H1l,
                       (const float*)nullptr, (float*)nullptr, NN, HD, HD2);
  };
  auto mode2 = [&](float* score){
    hipLaunchKernelGGL((k_mfma_gemm<2>), dim3(GX, 2), dim3(256), 0, stream,
                       H1h, H1l, m2h, m2l, (const u16*)nullptr, (const u16*)nullptr,
                       b2, (float*)nullptr, (u16*)nullptr, (u16*)nullptr,
                       m3, score, NN, HD2, HD2);
  };
  auto gemm0 = [&](int i){
    hipLaunchKernelGGL((k_mfma_gemm<0>), dim3(GX, 1), dim3(256), 0, stream,
                       Xh, Xl, wth[i], wtl[i], (const u16*)nullptr, (const u16*)nullptr,
                       (const float*)nullptr, y, (u16*)nullptr, (u16*)nullptr,
                       (const float*)nullptr, (float*)nullptr, NN, HD, HD);
  };
  auto fused01 = [&](int i){
    hipLaunchKernelGGL((k_mfma_gemm<3>), dim3(GX, 3), dim3(256), 0, stream,
                       Xh, Xl, wth[i], wtl[i], m1h, m1l,
                       b1, y, H1h, H1l,
                       (const float*)nullptr, (float*)nullptr, NN, HD, 0);
  };

  for(int b = 0; b < 2; b++){
    const int* rp = b ? c2ptr : c1ptr;
    const uint2* ecv = b ? ecv2 : ecv1;
    float* score = sc + (size_t)b * NN;
    hipLaunchKernelGGL((k_spmm<true>), dim3(cdiv(NN, 4)), dim3(256), 0, stream,
                       rp, ecv, w1, Xh, Xl);
    if(ded_y){
      // spmm; 8x [fused01(h1,y); mode2; spmm]; mode1; mode2
      for(int i = 0; i < 8; i++){
        fused01(i);
        mode2(score);
        if(i < 7)
          hipLaunchKernelGGL((k_spmm<true>),  dim3(cdiv(NN, 4)), dim3(256), 0, stream,
                             rp, ecv, y, Xh, Xl);
        else
          hipLaunchKernelGGL((k_spmm<false>), dim3(cdiv(NN, 4)), dim3(256), 0, stream,
                             rp, ecv, y, Xh, Xl);
      }
      mode1();
      mode2(score);
    } else {
      // r6-proven serial order (y aliases H1h)
      mode1();
      mode2(score);
      for(int i = 0; i < 8; i++){
        gemm0(i);
        if(i < 7)
          hipLaunchKernelGGL((k_spmm<true>),  dim3(cdiv(NN, 4)), dim3(256), 0, stream,
                             rp, ecv, y, Xh, Xl);
        else
          hipLaunchKernelGGL((k_spmm<false>), dim3(cdiv(NN, 4)), dim3(256), 0, stream,
                             rp, ecv, y, Xh, Xl);
        mode1();
        mode2(score);
      }
    }
  }

  hipLaunchKernelGGL(k_final, dim3(cdiv(NN, 256)), dim3(256), 0, stream, sc, b3, out);
}

// Round 4
// 4401.665 us; speedup vs baseline: 1.6604x; 1.6604x over previous
//
#include <hip/hip_runtime.h>
#include <hip/hip_fp16.h>

#define NN 100000
#define NE 1600000
#define HD 128
#define HD2 256

// binned scatter params
#define NBK 512
#define RPB 196      // rows per bucket; 512*196 = 100352 >= NN
#define CH  4096     // edges per binscatter block

typedef unsigned int u32;
typedef unsigned short u16;
typedef _Float16 half8 __attribute__((ext_vector_type(8)));
typedef float floatx4 __attribute__((ext_vector_type(4)));

static inline int cdiv(int a, int b){ return (a + b - 1) / b; }

// ---- split-fp16 packing: x ~= h + l * 2^-12, l pre-scaled by 4096 ----
__device__ __forceinline__ u32 split_pack(float v){
  __half h;
  if(fabsf(v) < 6.103515625e-05f) h = __ushort_as_half((u16)0);
  else h = __float2half_rn(v);
  float hf = __half2float(h);
  __half l = __float2half_rn((v - hf) * 4096.0f);
  return (u32)__half_as_ushort(h) | ((u32)__half_as_ushort(l) << 16);
}

// ---------------- utility kernels ----------------
__global__ void k_zero_int(int* __restrict__ p, int n){
  int i = blockIdx.x * 256 + threadIdx.x;
  if(i < n) p[i] = 0;
}

__global__ void k_zero_f(float* __restrict__ p, int n){
  int i = blockIdx.x * 256 + threadIdx.x;
  if(i < n) p[i] = 0.f;
}

// ---------------- batched CSR build (blockIdx.y = adjacency), packed (col,val) ----------------
__global__ void k_hist2(const int* __restrict__ r0, const int* __restrict__ r1,
                        int* __restrict__ cnt){
  int e = blockIdx.x * 256 + threadIdx.x;
  if(e < NE){
    const int* rows = blockIdx.y ? r1 : r0;
    atomicAdd(&cnt[blockIdx.y * NN + rows[e]], 1);
  }
}

__global__ void k_scan1b(const int* __restrict__ cnt, int* __restrict__ p0,
                         int* __restrict__ p1, int* __restrict__ sums, int n){
  __shared__ int sh[256];
  int z = blockIdx.y;
  const int* c = cnt + z * n;
  int* part = z ? p1 : p0;
  int* sm = sums + z * 128;
  int tid = threadIdx.x;
  int base = blockIdx.x * 1024 + tid * 4;
  int v0 = (base + 0 < n) ? c[base + 0] : 0;
  int v1 = (base + 1 < n) ? c[base + 1] : 0;
  int v2 = (base + 2 < n) ? c[base + 2] : 0;
  int v3 = (base + 3 < n) ? c[base + 3] : 0;
  int s = v0 + v1 + v2 + v3;
  sh[tid] = s;
  __syncthreads();
  for(int d = 1; d < 256; d <<= 1){
    int t = (tid >= d) ? sh[tid - d] : 0;
    __syncthreads();
    sh[tid] += t;
    __syncthreads();
  }
  int excl = sh[tid] - s;
  if(tid == 255) sm[blockIdx.x] = sh[255];
  if(base + 0 < n) part[base + 0] = excl;
  if(base + 1 < n) part[base + 1] = excl + v0;
  if(base + 2 < n) part[base + 2] = excl + v0 + v1;
  if(base + 3 < n) part[base + 3] = excl + v0 + v1 + v2;
}

__global__ void k_scan2b(int* __restrict__ sums, int nb){
  __shared__ int sh[128];
  int* s = sums + blockIdx.x * 128;
  int tid = threadIdx.x;
  int v = (tid < nb) ? s[tid] : 0;
  sh[tid] = v;
  __syncthreads();
  for(int d = 1; d < 128; d <<= 1){
    int t = (tid >= d) ? sh[tid - d] : 0;
    __syncthreads();
    sh[tid] += t;
    __syncthreads();
  }
  if(tid < nb) s[tid] = sh[tid] - v;
}

__global__ void k_scan3b(int* __restrict__ r0, int* __restrict__ r1,
                         int* __restrict__ cursor, const int* __restrict__ sums, int n){
  int z = blockIdx.y;
  int* rowptr = z ? r1 : r0;
  int* cur = cursor + z * n;
  int off = sums[z * 128 + blockIdx.x];
  int tid = threadIdx.x;
  int base = blockIdx.x * 1024 + tid * 4;
  #pragma unroll
  for(int j = 0; j < 4; j++){
    int idx = base + j;
    if(idx < n){ int r = rowptr[idx] + off; rowptr[idx] = r; cur[idx] = r; }
  }
  if(blockIdx.x == 0 && tid == 0) rowptr[n] = NE;
}

// bucket cursor init: bucket b starts at rowptr[min(b*RPB, NN)]
__global__ void k_init_bcur(const int* __restrict__ c1ptr, const int* __restrict__ c2ptr,
                            int* __restrict__ cursor){
  int b = blockIdx.x * 256 + threadIdx.x;
  int z = blockIdx.y;
  if(b < NBK){
    const int* rp = z ? c2ptr : c1ptr;
    int r = b * RPB; if(r > NN) r = NN;
    cursor[z * NN + b] = rp[r];
  }
}

// pass B: LDS-binned scatter into bucket-contiguous staging (burst writes)
__global__ void k_binscatter(const int* __restrict__ r0a, const int* __restrict__ c0a,
                             const float* __restrict__ v0a,
                             const int* __restrict__ r1a, const int* __restrict__ c1a,
                             const float* __restrict__ v1a,
                             int* __restrict__ bcur,
                             u32* __restrict__ sr0, uint2* __restrict__ sv0,
                             u32* __restrict__ sr1, uint2* __restrict__ sv1){
  __shared__ int cnt[NBK];
  __shared__ int bstart[NBK];
  __shared__ int gbase[NBK];
  __shared__ int sh[256];
  __shared__ u32 srow[CH];
  __shared__ uint2 scvs[CH];
  int z = blockIdx.y;
  const int* rows = z ? r1a : r0a;
  const int* cols = z ? c1a : c0a;
  const float* vals = z ? v1a : v0a;
  int* cur = bcur + z * NN;
  u32* osr = z ? sr1 : sr0;
  uint2* osv = z ? sv1 : sv0;
  int t = threadIdx.x;
  for(int i = t; i < NBK; i += 256) cnt[i] = 0;
  __syncthreads();
  int e0 = blockIdx.x * CH;
  int total = NE - e0; if(total > CH) total = CH;
  int r_[16], c_[16], b_[16], k_[16]; float v_[16];
  #pragma unroll
  for(int k = 0; k < 16; k++){
    int e = e0 + t + k * 256;
    b_[k] = -1;
    if(e < NE){
      r_[k] = rows[e]; c_[k] = cols[e]; v_[k] = vals[e];
      b_[k] = r_[k] / RPB;
      k_[k] = atomicAdd(&cnt[b_[k]], 1);
    }
  }
  __syncthreads();
  // exclusive scan of cnt[512] with 256 threads (2 elems/thread)
  int v0 = cnt[2 * t], v1 = cnt[2 * t + 1];
  int s2 = v0 + v1;
  sh[t] = s2;
  __syncthreads();
  for(int d = 1; d < 256; d <<= 1){
    int tv = (t >= d) ? sh[t - d] : 0;
    __syncthreads();
    sh[t] += tv;
    __syncthreads();
  }
  int excl = sh[t] - s2;
  bstart[2 * t] = excl;
  bstart[2 * t + 1] = excl + v0;
  __syncthreads();
  // stage into LDS sorted-by-bucket
  #pragma unroll
  for(int k = 0; k < 16; k++){
    if(b_[k] >= 0){
      int slot = bstart[b_[k]] + k_[k];
      srow[slot] = (u32)r_[k];
      scvs[slot] = make_uint2((u32)c_[k], __float_as_uint(v_[k]));
    }
  }
  // reserve global space per bucket (one atomic per non-empty bucket)
  for(int b = t; b < NBK; b += 256){
    int c = cnt[b];
    if(c > 0) gbase[b] = atomicAdd(&cur[b], c);
  }
  __syncthreads();
  // burst write-out: consecutive i -> same bucket -> contiguous dest
  for(int i = t; i < total; i += 256){
    u32 r = srow[i];
    int b = (int)r / RPB;
    int dest = gbase[b] + (i - bstart[b]);
    osr[dest] = r;
    osv[dest] = scvs[i];
  }
}

// pass C: per-bucket placement into final CSR order (dest region ~25KB, L2-hot)
__global__ void k_bucket_place(const int* __restrict__ c1ptr, const int* __restrict__ c2ptr,
                               const u32* __restrict__ sr0, const uint2* __restrict__ sv0,
                               const u32* __restrict__ sr1, const uint2* __restrict__ sv1,
                               uint2* __restrict__ e0, uint2* __restrict__ e1){
  __shared__ int cur[RPB];
  int z = blockIdx.y;
  const int* rp = z ? c2ptr : c1ptr;
  const u32* sr = z ? sr1 : sr0;
  const uint2* sv = z ? sv1 : sv0;
  uint2* ecv = z ? e1 : e0;
  int b = blockIdx.x;
  int r0 = b * RPB;
  if(r0 >= NN) return;
  int rend = r0 + RPB; if(rend > NN) rend = NN;
  int t = threadIdx.x;
  for(int r = t; r < rend - r0; r += 256) cur[r] = rp[r0 + r];
  __syncthreads();
  int s = rp[r0], e = rp[rend];
  for(int i = s + t; i < e; i += 256){
    u32 r = sr[i];
    uint2 cv = sv[i];
    int p = atomicAdd(&cur[r - r0], 1);
    ecv[p] = cv;
  }
}

// weight pre-split: W is [K][N] row-major fp32; out is packed [N][K] (transposed)
__global__ void k_splitw(const float* __restrict__ W, u32* __restrict__ out,
                         int K, int N, int total){
  int idx = blockIdx.x * 256 + threadIdx.x;
  if(idx < total){
    int n = idx / K, k = idx - n * K;
    out[idx] = split_pack(W[(size_t)k * N + n]);
  }
}

// ---------------- SpMM: one wave per node; relu (+ optional l2norm); packed-split output ----
template<bool NORM>
__global__ void k_spmm(const int* __restrict__ rowptr, const uint2* __restrict__ ecv,
                       const float* __restrict__ X, u32* __restrict__ outpk){
  int node = (blockIdx.x << 2) + (threadIdx.x >> 6);
  int lane = threadIdx.x & 63;
  if(node >= NN) return;
  int s = rowptr[node], e = rowptr[node + 1];
  float ax = 0.f, ay = 0.f, bx = 0.f, by = 0.f;
  int i = s;
  for(; i + 15 < e; i += 16){
    uint2 ee[16]; float2 xx[16];
    #pragma unroll
    for(int j = 0; j < 16; j++) ee[j] = ecv[i + j];
    #pragma unroll
    for(int j = 0; j < 16; j++) xx[j] = *(const float2*)(X + (size_t)ee[j].x * HD + lane * 2);
    #pragma unroll
    for(int j = 0; j < 16; j += 4){
      ax += __uint_as_float(ee[j].y)   * xx[j].x   + __uint_as_float(ee[j+1].y) * xx[j+1].x;
      ay += __uint_as_float(ee[j].y)   * xx[j].y   + __uint_as_float(ee[j+1].y) * xx[j+1].y;
      bx += __uint_as_float(ee[j+2].y) * xx[j+2].x + __uint_as_float(ee[j+3].y) * xx[j+3].x;
      by += __uint_as_float(ee[j+2].y) * xx[j+2].y + __uint_as_float(ee[j+3].y) * xx[j+3].y;
    }
  }
  for(; i + 3 < e; i += 4){
    uint2 f0 = ecv[i], f1 = ecv[i+1], f2 = ecv[i+2], f3 = ecv[i+3];
    float2 x0 = *(const float2*)(X + (size_t)f0.x * HD + lane * 2);
    float2 x1 = *(const float2*)(X + (size_t)f1.x * HD + lane * 2);
    float2 x2 = *(const float2*)(X + (size_t)f2.x * HD + lane * 2);
    float2 x3 = *(const float2*)(X + (size_t)f3.x * HD + lane * 2);
    ax += __uint_as_float(f0.y) * x0.x + __uint_as_float(f1.y) * x1.x;
    ay += __uint_as_float(f0.y) * x0.y + __uint_as_float(f1.y) * x1.y;
    bx += __uint_as_float(f2.y) * x2.x + __uint_as_float(f3.y) * x3.x;
    by += __uint_as_float(f2.y) * x2.y + __uint_as_float(f3.y) * x3.y;
  }
  for(; i < e; i++){
    uint2 f0 = ecv[i];
    float2 xv = *(const float2*)(X + (size_t)f0.x * HD + lane * 2);
    ax += __uint_as_float(f0.y) * xv.x;
    ay += __uint_as_float(f0.y) * xv.y;
  }
  ax += bx; ay += by;
  ax = fmaxf(ax, 0.f);
  ay = fmaxf(ay, 0.f);
  if(NORM){
    float ss = ax * ax + ay * ay;
    #pragma unroll
    for(int o = 32; o >= 1; o >>= 1) ss += __shfl_xor(ss, o, 64);
    float scale = 1.f / fmaxf(sqrtf(ss), 1e-12f);
    ax *= scale; ay *= scale;
  }
  *(uint2*)(outpk + (size_t)node * HD + lane * 2) = make_uint2(split_pack(ax), split_pack(ay));
}

// ---------------- split-fp16 MFMA GEMM (round-6-proven body, XCD-paired col-tiles) ----
// 1-D grid. Block d -> (row-tile rt, col-tile ct) such that all NYC col-tiles of a
// row-panel land on the SAME XCD (d%8 equal), 8 dispatch slots apart -> the A panel
// is fetched from HBM once and L2-hit by the other col-tile(s).
// A: packed [M][K]; Bt: packed [N][K] (pre-transposed).
// MODE 0: Yout = A@B (fp32). MODE 1: Hout = pack(relu(A@B+bias)).
// MODE 2: score[m] += sum_n relu(A@B+bias)[m][n]*m3[n].
// MODE 3: fused — ct==0: mode0 with Bt0 -> Yout [M][HD];
//                 ct in {1,2}: mode1 col-tile with Bt1 -> Hout [M][HD2].
template<int MODE>
__launch_bounds__(256, 2)
__global__ void k_mfma_gemm(const u32* __restrict__ Apk, const u32* __restrict__ Btpk,
                            const u32* __restrict__ Bt1pk,
                            const float* __restrict__ bias, float* __restrict__ Yout,
                            u32* __restrict__ Hout, const float* __restrict__ m3,
                            float* __restrict__ score, int M, int K, int N){
  __shared__ u16 As_h[128 * 40], As_l[128 * 40];
  __shared__ u16 Bs_h[128 * 40], Bs_l[128 * 40];
  constexpr int NYC = (MODE == 0) ? 1 : ((MODE == 3) ? 3 : 2);
  const int d = blockIdx.x;
  const int grp = d / (8 * NYC);
  const int rem = d - grp * 8 * NYC;
  const int rt = grp * 8 + (rem & 7);
  const int ct = rem >> 3;
  const int nrt = (M + 127) >> 7;
  if(rt >= nrt) return;
  const int tid = threadIdx.x;
  const int lane = tid & 63, wid = tid >> 6;
  const int lm = lane & 15, lg = lane >> 4;
  const int mq = (wid & 1) * 64, nq = (wid >> 1) * 64;
  const int m0 = rt * 128;
  int n0 = ct * 128;
  const u32* Bt = Btpk;
  bool m0path = true;
  if(MODE == 3){
    m0path = (ct == 0);
    if(m0path){ n0 = 0; }
    else      { n0 = (ct - 1) * 128; Bt = Bt1pk; }
  }

  floatx4 accA[4][4], accB[4][4];
  #pragma unroll
  for(int i = 0; i < 4; i++)
    #pragma unroll
    for(int j = 0; j < 4; j++){
      accA[i][j] = (floatx4){0.f, 0.f, 0.f, 0.f};
      accB[i][j] = (floatx4){0.f, 0.f, 0.f, 0.f};
    }

  for(int k0 = 0; k0 < K; k0 += 32){
    uint4 av[4], bv[4];
    #pragma unroll
    for(int j = 0; j < 4; j++){
      int li = tid + j * 256;
      int row = li >> 3, kc = (li & 7) * 4;
      int ar = m0 + row; if(ar >= M) ar = M - 1;
      av[j] = *(const uint4*)(Apk + (size_t)ar * K + k0 + kc);
      bv[j] = *(const uint4*)(Bt + (size_t)(n0 + row) * K + k0 + kc);
    }
    if(k0) __syncthreads();
    #pragma unroll
    for(int j = 0; j < 4; j++){
      int li = tid + j * 256;
      int row = li >> 3, kc = (li & 7) * 4;
      int base = row * 40 + kc;
      ushort4 h, l;
      h.x = (u16)(av[j].x & 0xffff); l.x = (u16)(av[j].x >> 16);
      h.y = (u16)(av[j].y & 0xffff); l.y = (u16)(av[j].y >> 16);
      h.z = (u16)(av[j].z & 0xffff); l.z = (u16)(av[j].z >> 16);
      h.w = (u16)(av[j].w & 0xffff); l.w = (u16)(av[j].w >> 16);
      *(ushort4*)&As_h[base] = h;
      *(ushort4*)&As_l[base] = l;
      h.x = (u16)(bv[j].x & 0xffff); l.x = (u16)(bv[j].x >> 16);
      h.y = (u16)(bv[j].y & 0xffff); l.y = (u16)(bv[j].y >> 16);
      h.z = (u16)(bv[j].z & 0xffff); l.z = (u16)(bv[j].z >> 16);
      h.w = (u16)(bv[j].w & 0xffff); l.w = (u16)(bv[j].w >> 16);
      *(ushort4*)&Bs_h[base] = h;
      *(ushort4*)&Bs_l[base] = l;
    }
    __syncthreads();

    half8 fa_h[4], fa_l[4], fb_h[4], fb_l[4];
    #pragma unroll
    for(int s = 0; s < 4; s++){
      int ra = (mq + s * 16 + lm) * 40 + lg * 8;
      fa_h[s] = *(const half8*)&As_h[ra];
      fa_l[s] = *(const half8*)&As_l[ra];
      int rb = (nq + s * 16 + lm) * 40 + lg * 8;
      fb_h[s] = *(const half8*)&Bs_h[rb];
      fb_l[s] = *(const half8*)&Bs_l[rb];
    }
    #pragma unroll
    for(int i = 0; i < 4; i++)
      #pragma unroll
      for(int j = 0; j < 4; j++){
        accA[i][j] = __builtin_amdgcn_mfma_f32_16x16x32_f16(fa_h[i], fb_h[j], accA[i][j], 0, 0, 0);
        accB[i][j] = __builtin_amdgcn_mfma_f32_16x16x32_f16(fa_h[i], fb_l[j], accB[i][j], 0, 0, 0);
        accB[i][j] = __builtin_amdgcn_mfma_f32_16x16x32_f16(fa_l[i], fb_h[j], accB[i][j], 0, 0, 0);
      }
  }

  const float inv4096 = 1.f / 4096.f;
  if(MODE == 0 || (MODE == 3 && m0path)){
    int ldy = (MODE == 3) ? HD : N;
    #pragma unroll
    for(int i = 0; i < 4; i++)
      #pragma unroll
      for(int r = 0; r < 4; r++){
        int m = m0 + mq + i * 16 + lg * 4 + r;
        if(m < M){
          #pragma unroll
          for(int j = 0; j < 4; j++){
            int c = n0 + nq + j * 16 + lm;
            Yout[(size_t)m * ldy + c] = accA[i][j][r] + accB[i][j][r] * inv4096;
          }
        }
      }
  } else if(MODE == 1 || MODE == 3){
    int ldh = (MODE == 3) ? HD2 : N;
    #pragma unroll
    for(int i = 0; i < 4; i++)
      #pragma unroll
      for(int r = 0; r < 4; r++){
        int m = m0 + mq + i * 16 + lg * 4 + r;
        if(m < M){
          #pragma unroll
          for(int j = 0; j < 4; j++){
            int c = n0 + nq + j * 16 + lm;
            float v = fmaxf(accA[i][j][r] + accB[i][j][r] * inv4096 + bias[c], 0.f);
            Hout[(size_t)m * ldh + c] = split_pack(v);
          }
        }
      }
  } else {
    #pragma unroll
    for(int i = 0; i < 4; i++)
      #pragma unroll
      for(int r = 0; r < 4; r++){
        float s = 0.f;
        #pragma unroll
        for(int j = 0; j < 4; j++){
          int c = n0 + nq + j * 16 + lm;
          float v = fmaxf(accA[i][j][r] + accB[i][j][r] * inv4096 + bias[c], 0.f);
          s = fmaf(v, m3[c], s);
        }
        s += __shfl_xor(s, 1, 64);
        s += __shfl_xor(s, 2, 64);
        s += __shfl_xor(s, 4, 64);
        s += __shfl_xor(s, 8, 64);
        int m = m0 + mq + i * 16 + lg * 4 + r;
        if(lm == 0 && m < M) atomicAdd(&score[m], s);
      }
  }
}

__global__ void k_final(const float* __restrict__ sc, const float* __restrict__ b3,
                        float* __restrict__ out){
  int i = blockIdx.x * 256 + threadIdx.x;
  if(i < NN){
    float b = 9.f * b3[0];
    out[i] = (sc[i] + b) * (sc[NN + i] + b);
  }
}

// ---------------- launcher ----------------
extern "C" void kernel_launch(void* const* d_in, const int* in_sizes, int n_in,
                              void* d_out, int out_size, void* d_ws, size_t ws_size,
                              hipStream_t stream){
  const int*   a1r = (const int*)d_in[0];
  const int*   a1c = (const int*)d_in[1];
  const float* a1v = (const float*)d_in[2];
  const int*   a2r = (const int*)d_in[3];
  const int*   a2c = (const int*)d_in[4];
  const float* a2v = (const float*)d_in[5];
  const float* w1  = (const float*)d_in[6];
  const float* w[8];
  for(int i = 0; i < 8; i++) w[i] = (const float*)d_in[7 + i];
  const float* m1 = (const float*)d_in[15];
  const float* b1 = (const float*)d_in[16];
  const float* m2 = (const float*)d_in[17];
  const float* b2 = (const float*)d_in[18];
  const float* m3 = (const float*)d_in[19];
  const float* b3 = (const float*)d_in[20];
  float* out = (float*)d_out;

  char* base = (char*)d_ws;
  size_t off = 0;
  auto alloc = [&](size_t bytes) -> char* {
    char* r = base + off;
    off += (bytes + 255) & ~(size_t)255;
    return r;
  };
  int*   c1ptr = (int*)  alloc((size_t)(NN + 1) * 4);
  int*   c2ptr = (int*)  alloc((size_t)(NN + 1) * 4);
  uint2* ecv1  = (uint2*)alloc((size_t)NE * 8);
  uint2* ecv2  = (uint2*)alloc((size_t)NE * 8);
  int*   cursor= (int*)  alloc((size_t)2 * NN * 4);
  int*   sums  = (int*)  alloc(1024);
  float* sc    = (float*)alloc((size_t)2 * NN * 4);
  u32*   wtpk[8];
  for(int i = 0; i < 8; i++) wtpk[i] = (u32*)alloc((size_t)HD * HD * 4);
  u32*   m1tpk = (u32*)alloc((size_t)HD2 * HD * 4);
  u32*   m2tpk = (u32*)alloc((size_t)HD2 * HD2 * 4);
  u32*   xpk   = (u32*)alloc((size_t)NN * HD * 4);
  u32*   h1pk  = (u32*)alloc((size_t)NN * HD2 * 4);
  // fused01 tier needs dedicated y (fp32 [NN][HD]); else alias h1pk and run r6 schedule
  size_t need_ded = off + (((size_t)NN * HD * 4 + 255) & ~(size_t)255);
  bool ded_y = (ws_size >= need_ded);
  float* y = ded_y ? (float*)alloc((size_t)NN * HD * 4) : (float*)h1pk;

  // binned-scatter staging aliases h1pk (dead during CSR build): 38.4MB < 102.4MB
  char* hb = (char*)h1pk;
  uint2* sv1 = (uint2*)hb;
  u32*   sr1 = (u32*)(hb + (size_t)NE * 8);
  uint2* sv2 = (uint2*)(hb + (size_t)NE * 12);
  u32*   sr2 = (u32*)(hb + (size_t)NE * 20);

  // ---- batched CSR build (both adjacencies) ----
  hipLaunchKernelGGL(k_zero_int, dim3(cdiv(2 * NN, 256)), dim3(256), 0, stream, cursor, 2 * NN);
  hipLaunchKernelGGL(k_hist2, dim3(cdiv(NE, 256), 2), dim3(256), 0, stream, a1r, a2r, cursor);
  const int SCAN_BLOCKS = cdiv(NN, 1024);
  hipLaunchKernelGGL(k_scan1b, dim3(SCAN_BLOCKS, 2), dim3(256), 0, stream, cursor, c1ptr, c2ptr, sums, NN);
  hipLaunchKernelGGL(k_scan2b, dim3(2), dim3(128), 0, stream, sums, SCAN_BLOCKS);
  hipLaunchKernelGGL(k_scan3b, dim3(SCAN_BLOCKS, 2), dim3(256), 0, stream, c1ptr, c2ptr, cursor, sums, NN);
  hipLaunchKernelGGL(k_init_bcur, dim3(cdiv(NBK, 256), 2), dim3(256), 0, stream, c1ptr, c2ptr, cursor);
  hipLaunchKernelGGL(k_binscatter, dim3(cdiv(NE, CH), 2), dim3(256), 0, stream,
                     a1r, a1c, a1v, a2r, a2c, a2v, cursor, sr1, sv1, sr2, sv2);
  hipLaunchKernelGGL(k_bucket_place, dim3(NBK, 2), dim3(256), 0, stream,
                     c1ptr, c2ptr, sr1, sv1, sr2, sv2, ecv1, ecv2);

  auto splitw = [&](const float* W, u32* o, int K, int N){
    int total = K * N;
    hipLaunchKernelGGL(k_splitw, dim3(cdiv(total, 256)), dim3(256), 0, stream, W, o, K, N, total);
  };
  for(int i = 0; i < 8; i++) splitw(w[i], wtpk[i], HD, HD);
  splitw(m1, m1tpk, HD, HD2);
  splitw(m2, m2tpk, HD2, HD2);
  hipLaunchKernelGGL(k_zero_f, dim3(cdiv(2 * NN, 256)), dim3(256), 0, stream, sc, 2 * NN);

  const int NRT = cdiv(NN, 128);          // 782 row tiles
  const int GP  = cdiv(NRT, 8) * 8;       // 784 padded rows
  auto mode1 = [&](){
    hipLaunchKernelGGL((k_mfma_gemm<1>), dim3(GP * 2), dim3(256), 0, stream,
                       xpk, m1tpk, (const u32*)nullptr, b1, (float*)nullptr, h1pk,
                       (const float*)nullptr, (float*)nullptr, NN, HD, HD2);
  };
  auto mode2 = [&](float* score){
    hipLaunchKernelGGL((k_mfma_gemm<2>), dim3(GP * 2), dim3(256), 0, stream,
                       h1pk, m2tpk, (const u32*)nullptr, b2, (float*)nullptr, (u32*)nullptr,
                       m3, score, NN, HD2, HD2);
  };
  auto gemm0 = [&](int i){
    hipLaunchKernelGGL((k_mfma_gemm<0>), dim3(GP * 1), dim3(256), 0, stream,
                       xpk, wtpk[i], (const u32*)nullptr, (const float*)nullptr, y, (u32*)nullptr,
                       (const float*)nullptr, (float*)nullptr, NN, HD, HD);
  };
  auto fused01 = [&](int i){
    hipLaunchKernelGGL((k_mfma_gemm<3>), dim3(GP * 3), dim3(256), 0, stream,
                       xpk, wtpk[i], m1tpk, b1, y, h1pk,
                       (const float*)nullptr, (float*)nullptr, NN, HD, 0);
  };

  for(int b = 0; b < 2; b++){
    const int* rp = b ? c2ptr : c1ptr;
    const uint2* ecv = b ? ecv2 : ecv1;
    float* score = sc + (size_t)b * NN;
    hipLaunchKernelGGL((k_spmm<true>), dim3(cdiv(NN, 4)), dim3(256), 0, stream,
                       rp, ecv, w1, xpk);
    if(ded_y){
      // spmm; 8x [fused01(h1,y); mode2; spmm]; mode1; mode2
      for(int i = 0; i < 8; i++){
        fused01(i);
        mode2(score);
        if(i < 7)
          hipLaunchKernelGGL((k_spmm<true>),  dim3(cdiv(NN, 4)), dim3(256), 0, stream,
                             rp, ecv, y, xpk);
        else
          hipLaunchKernelGGL((k_spmm<false>), dim3(cdiv(NN, 4)), dim3(256), 0, stream,
                             rp, ecv, y, xpk);
      }
      mode1();
      mode2(score);
    } else {
      // r6-proven serial order (y aliases h1pk)
      mode1();
      mode2(score);
      for(int i = 0; i < 8; i++){
        gemm0(i);
        if(i < 7)
          hipLaunchKernelGGL((k_spmm<true>),  dim3(cdiv(NN, 4)), dim3(256), 0, stream,
                             rp, ecv, y, xpk);
        else
          hipLaunchKernelGGL((k_spmm<false>), dim3(cdiv(NN, 4)), dim3(256), 0, stream,
                             rp, ecv, y, xpk);
        mode1();
        mode2(score);
      }
    }
  }

  hipLaunchKernelGGL(k_final, dim3(cdiv(NN, 256)), dim3(256), 0, stream, sc, b3, out);
}

// Round 5
// 4282.445 us; speedup vs baseline: 1.7066x; 1.0278x over previous
//
#include <hip/hip_runtime.h>
#include <hip/hip_fp16.h>

#define NN 100000
#define NE 1600000
#define HD 128
#define HD2 256

// binned scatter params
#define NBK 512
#define RPB 196      // rows per bucket; 512*196 = 100352 >= NN
#define CH  4096     // edges per binscatter block
#define CAP 4096     // staging capacity per bucket (17-sigma above mean 3136)

typedef unsigned int u32;
typedef unsigned short u16;
typedef _Float16 half8 __attribute__((ext_vector_type(8)));
typedef float floatx4 __attribute__((ext_vector_type(4)));

static inline int cdiv(int a, int b){ return (a + b - 1) / b; }

// ---- split-fp16 packing: x ~= h + l * 2^-12, l pre-scaled by 4096 ----
__device__ __forceinline__ u32 split_pack(float v){
  __half h;
  if(fabsf(v) < 6.103515625e-05f) h = __ushort_as_half((u16)0);
  else h = __float2half_rn(v);
  float hf = __half2float(h);
  __half l = __float2half_rn((v - hf) * 4096.0f);
  return (u32)__half_as_ushort(h) | ((u32)__half_as_ushort(l) << 16);
}

// ---------------- utility kernels ----------------
__global__ void k_zero_f(float* __restrict__ p, int n){
  int i = blockIdx.x * 256 + threadIdx.x;
  if(i < n) p[i] = 0.f;
}

// bucket cursor init: staging region for bucket b starts at b*CAP
__global__ void k_init_bcap(int* __restrict__ bcur){
  int i = blockIdx.x * 256 + threadIdx.x;
  if(i < 2 * NBK) bcur[i] = (i & (NBK - 1)) * CAP;
}

// pass B: LDS-binned scatter into fixed-capacity bucket staging (burst writes)
__global__ void k_binscatter(const int* __restrict__ r0a, const int* __restrict__ c0a,
                             const float* __restrict__ v0a,
                             const int* __restrict__ r1a, const int* __restrict__ c1a,
                             const float* __restrict__ v1a,
                             int* __restrict__ bcur,
                             u32* __restrict__ sr0, uint2* __restrict__ sv0,
                             u32* __restrict__ sr1, uint2* __restrict__ sv1){
  __shared__ int cnt[NBK];
  __shared__ int bstart[NBK];
  __shared__ int gbase[NBK];
  __shared__ int sh[256];
  __shared__ u32 srow[CH];
  __shared__ uint2 scvs[CH];
  int z = blockIdx.y;
  const int* rows = z ? r1a : r0a;
  const int* cols = z ? c1a : c0a;
  const float* vals = z ? v1a : v0a;
  int* cur = bcur + z * NBK;
  u32* osr = z ? sr1 : sr0;
  uint2* osv = z ? sv1 : sv0;
  int t = threadIdx.x;
  for(int i = t; i < NBK; i += 256) cnt[i] = 0;
  __syncthreads();
  int e0 = blockIdx.x * CH;
  int total = NE - e0; if(total > CH) total = CH;
  int r_[16], c_[16], b_[16], k_[16]; float v_[16];
  #pragma unroll
  for(int k = 0; k < 16; k++){
    int e = e0 + t + k * 256;
    b_[k] = -1;
    if(e < NE){
      r_[k] = rows[e]; c_[k] = cols[e]; v_[k] = vals[e];
      b_[k] = r_[k] / RPB;
      k_[k] = atomicAdd(&cnt[b_[k]], 1);
    }
  }
  __syncthreads();
  // exclusive scan of cnt[512] with 256 threads (2 elems/thread)
  int v0 = cnt[2 * t], v1 = cnt[2 * t + 1];
  int s2 = v0 + v1;
  sh[t] = s2;
  __syncthreads();
  for(int d = 1; d < 256; d <<= 1){
    int tv = (t >= d) ? sh[t - d] : 0;
    __syncthreads();
    sh[t] += tv;
    __syncthreads();
  }
  int excl = sh[t] - s2;
  bstart[2 * t] = excl;
  bstart[2 * t + 1] = excl + v0;
  __syncthreads();
  // stage into LDS sorted-by-bucket
  #pragma unroll
  for(int k = 0; k < 16; k++){
    if(b_[k] >= 0){
      int slot = bstart[b_[k]] + k_[k];
      srow[slot] = (u32)r_[k];
      scvs[slot] = make_uint2((u32)c_[k], __float_as_uint(v_[k]));
    }
  }
  // reserve staging space per bucket (one atomic per non-empty bucket)
  for(int b = t; b < NBK; b += 256){
    int c = cnt[b];
    if(c > 0) gbase[b] = atomicAdd(&cur[b], c);
  }
  __syncthreads();
  // burst write-out: consecutive i -> same bucket -> contiguous dest
  for(int i = t; i < total; i += 256){
    u32 r = srow[i];
    int b = (int)r / RPB;
    int dest = gbase[b] + (i - bstart[b]);
    osr[dest] = r;
    osv[dest] = scvs[i];
  }
}

// bucket totals -> global bucket bases (exclusive scan over 512), + rowptr[NN]=NE
__global__ void k_bucket_scan(const int* __restrict__ bcur, int* __restrict__ bbase,
                              int* __restrict__ c1ptr, int* __restrict__ c2ptr){
  __shared__ int sh[256];
  int z = blockIdx.x;
  const int* cur = bcur + z * NBK;
  int* bb = bbase + z * NBK;
  int t = threadIdx.x;
  int v0 = cur[2 * t]     - (2 * t) * CAP;
  int v1 = cur[2 * t + 1] - (2 * t + 1) * CAP;
  int s2 = v0 + v1;
  sh[t] = s2;
  __syncthreads();
  for(int d = 1; d < 256; d <<= 1){
    int tv = (t >= d) ? sh[t - d] : 0;
    __syncthreads();
    sh[t] += tv;
    __syncthreads();
  }
  int excl = sh[t] - s2;
  bb[2 * t] = excl;
  bb[2 * t + 1] = excl + v0;
  if(t == 0){
    int* rp = z ? c2ptr : c1ptr;
    rp[NN] = NE;
  }
}

// pass C: per-bucket — LDS row-histogram + local scan -> rowptr, then CSR placement
__global__ void k_bucket_place(const int* __restrict__ bcur, const int* __restrict__ bbase,
                               const u32* __restrict__ sr0, const uint2* __restrict__ sv0,
                               const u32* __restrict__ sr1, const uint2* __restrict__ sv1,
                               int* __restrict__ c1ptr, int* __restrict__ c2ptr,
                               uint2* __restrict__ e0, uint2* __restrict__ e1){
  __shared__ int hist[RPB];
  __shared__ int cur[RPB];
  __shared__ int sh[256];
  __shared__ u32 srows[CAP];
  int z = blockIdx.y;
  int b = blockIdx.x;
  int r0 = b * RPB;
  if(r0 >= NN) return;
  int rend = r0 + RPB; if(rend > NN) rend = NN;
  int nr = rend - r0;
  const u32* sr = z ? sr1 : sr0;
  const uint2* sv = z ? sv1 : sv0;
  int* rp = z ? c2ptr : c1ptr;
  uint2* ecv = z ? e1 : e0;
  int cnt = bcur[z * NBK + b] - b * CAP;
  int base = bbase[z * NBK + b];
  int g = b * CAP;
  int t = threadIdx.x;
  for(int r = t; r < nr; r += 256) hist[r] = 0;
  __syncthreads();
  for(int i = t; i < cnt; i += 256){
    u32 r = sr[g + i];
    srows[i] = r;
    atomicAdd(&hist[(int)r - r0], 1);
  }
  __syncthreads();
  int v = (t < nr) ? hist[t] : 0;
  sh[t] = v;
  __syncthreads();
  for(int d = 1; d < 256; d <<= 1){
    int tv = (t >= d) ? sh[t - d] : 0;
    __syncthreads();
    sh[t] += tv;
    __syncthreads();
  }
  int excl = sh[t] - v;
  if(t < nr){
    rp[r0 + t] = base + excl;
    cur[t] = base + excl;
  }
  __syncthreads();
  for(int i = t; i < cnt; i += 256){
    int r = (int)srows[i] - r0;
    int p = atomicAdd(&cur[r], 1);
    ecv[p] = sv[g + i];
  }
}

// weight pre-split: W is [K][N] row-major fp32; out is packed [N][K] (transposed)
__global__ void k_splitw(const float* __restrict__ W, u32* __restrict__ out,
                         int K, int N, int total){
  int idx = blockIdx.x * 256 + threadIdx.x;
  if(idx < total){
    int n = idx / K, k = idx - n * K;
    out[idx] = split_pack(W[(size_t)k * N + n]);
  }
}

// ---------------- SpMM: one wave per node; relu (+ optional l2norm); packed-split output ----
template<bool NORM>
__global__ void k_spmm(const int* __restrict__ rowptr, const uint2* __restrict__ ecv,
                       const float* __restrict__ X, u32* __restrict__ outpk){
  int node = (blockIdx.x << 2) + (threadIdx.x >> 6);
  int lane = threadIdx.x & 63;
  if(node >= NN) return;
  int s = rowptr[node], e = rowptr[node + 1];
  float ax = 0.f, ay = 0.f, bx = 0.f, by = 0.f;
  int i = s;
  for(; i + 15 < e; i += 16){
    uint2 ee[16]; float2 xx[16];
    #pragma unroll
    for(int j = 0; j < 16; j++) ee[j] = ecv[i + j];
    #pragma unroll
    for(int j = 0; j < 16; j++) xx[j] = *(const float2*)(X + (size_t)ee[j].x * HD + lane * 2);
    #pragma unroll
    for(int j = 0; j < 16; j += 4){
      ax += __uint_as_float(ee[j].y)   * xx[j].x   + __uint_as_float(ee[j+1].y) * xx[j+1].x;
      ay += __uint_as_float(ee[j].y)   * xx[j].y   + __uint_as_float(ee[j+1].y) * xx[j+1].y;
      bx += __uint_as_float(ee[j+2].y) * xx[j+2].x + __uint_as_float(ee[j+3].y) * xx[j+3].x;
      by += __uint_as_float(ee[j+2].y) * xx[j+2].y + __uint_as_float(ee[j+3].y) * xx[j+3].y;
    }
  }
  for(; i + 3 < e; i += 4){
    uint2 f0 = ecv[i], f1 = ecv[i+1], f2 = ecv[i+2], f3 = ecv[i+3];
    float2 x0 = *(const float2*)(X + (size_t)f0.x * HD + lane * 2);
    float2 x1 = *(const float2*)(X + (size_t)f1.x * HD + lane * 2);
    float2 x2 = *(const float2*)(X + (size_t)f2.x * HD + lane * 2);
    float2 x3 = *(const float2*)(X + (size_t)f3.x * HD + lane * 2);
    ax += __uint_as_float(f0.y) * x0.x + __uint_as_float(f1.y) * x1.x;
    ay += __uint_as_float(f0.y) * x0.y + __uint_as_float(f1.y) * x1.y;
    bx += __uint_as_float(f2.y) * x2.x + __uint_as_float(f3.y) * x3.x;
    by += __uint_as_float(f2.y) * x2.y + __uint_as_float(f3.y) * x3.y;
  }
  for(; i < e; i++){
    uint2 f0 = ecv[i];
    float2 xv = *(const float2*)(X + (size_t)f0.x * HD + lane * 2);
    ax += __uint_as_float(f0.y) * xv.x;
    ay += __uint_as_float(f0.y) * xv.y;
  }
  ax += bx; ay += by;
  ax = fmaxf(ax, 0.f);
  ay = fmaxf(ay, 0.f);
  if(NORM){
    float ss = ax * ax + ay * ay;
    #pragma unroll
    for(int o = 32; o >= 1; o >>= 1) ss += __shfl_xor(ss, o, 64);
    float scale = 1.f / fmaxf(sqrtf(ss), 1e-12f);
    ax *= scale; ay *= scale;
  }
  *(uint2*)(outpk + (size_t)node * HD + lane * 2) = make_uint2(split_pack(ax), split_pack(ay));
}

// ---------------- split-fp16 MFMA GEMM (round-6-proven body, XCD-paired col-tiles) ----
// 1-D grid. Block d -> (row-tile rt, col-tile ct) such that all NYC col-tiles of a
// row-panel land on the SAME XCD (d%8 equal), 8 dispatch slots apart -> the A panel
// is fetched from HBM once and L2-hit by the other col-tile(s).
// A: packed [M][K]; Bt: packed [N][K] (pre-transposed).
// MODE 0: Yout = A@B (fp32). MODE 1: Hout = pack(relu(A@B+bias)).
// MODE 2: score[m] += sum_n relu(A@B+bias)[m][n]*m3[n].
// MODE 3: fused — ct==0: mode0 with Bt0 -> Yout [M][HD];
//                 ct in {1,2}: mode1 col-tile with Bt1 -> Hout [M][HD2].
template<int MODE>
__launch_bounds__(256, 2)
__global__ void k_mfma_gemm(const u32* __restrict__ Apk, const u32* __restrict__ Btpk,
                            const u32* __restrict__ Bt1pk,
                            const float* __restrict__ bias, float* __restrict__ Yout,
                            u32* __restrict__ Hout, const float* __restrict__ m3,
                            float* __restrict__ score, int M, int K, int N){
  __shared__ u16 As_h[128 * 40], As_l[128 * 40];
  __shared__ u16 Bs_h[128 * 40], Bs_l[128 * 40];
  constexpr int NYC = (MODE == 0) ? 1 : ((MODE == 3) ? 3 : 2);
  const int d = blockIdx.x;
  const int grp = d / (8 * NYC);
  const int rem = d - grp * 8 * NYC;
  const int rt = grp * 8 + (rem & 7);
  const int ct = rem >> 3;
  const int nrt = (M + 127) >> 7;
  if(rt >= nrt) return;
  const int tid = threadIdx.x;
  const int lane = tid & 63, wid = tid >> 6;
  const int lm = lane & 15, lg = lane >> 4;
  const int mq = (wid & 1) * 64, nq = (wid >> 1) * 64;
  const int m0 = rt * 128;
  int n0 = ct * 128;
  const u32* Bt = Btpk;
  bool m0path = true;
  if(MODE == 3){
    m0path = (ct == 0);
    if(m0path){ n0 = 0; }
    else      { n0 = (ct - 1) * 128; Bt = Bt1pk; }
  }

  floatx4 accA[4][4], accB[4][4];
  #pragma unroll
  for(int i = 0; i < 4; i++)
    #pragma unroll
    for(int j = 0; j < 4; j++){
      accA[i][j] = (floatx4){0.f, 0.f, 0.f, 0.f};
      accB[i][j] = (floatx4){0.f, 0.f, 0.f, 0.f};
    }

  for(int k0 = 0; k0 < K; k0 += 32){
    uint4 av[4], bv[4];
    #pragma unroll
    for(int j = 0; j < 4; j++){
      int li = tid + j * 256;
      int row = li >> 3, kc = (li & 7) * 4;
      int ar = m0 + row; if(ar >= M) ar = M - 1;
      av[j] = *(const uint4*)(Apk + (size_t)ar * K + k0 + kc);
      bv[j] = *(const uint4*)(Bt + (size_t)(n0 + row) * K + k0 + kc);
    }
    if(k0) __syncthreads();
    #pragma unroll
    for(int j = 0; j < 4; j++){
      int li = tid + j * 256;
      int row = li >> 3, kc = (li & 7) * 4;
      int base = row * 40 + kc;
      ushort4 h, l;
      h.x = (u16)(av[j].x & 0xffff); l.x = (u16)(av[j].x >> 16);
      h.y = (u16)(av[j].y & 0xffff); l.y = (u16)(av[j].y >> 16);
      h.z = (u16)(av[j].z & 0xffff); l.z = (u16)(av[j].z >> 16);
      h.w = (u16)(av[j].w & 0xffff); l.w = (u16)(av[j].w >> 16);
      *(ushort4*)&As_h[base] = h;
      *(ushort4*)&As_l[base] = l;
      h.x = (u16)(bv[j].x & 0xffff); l.x = (u16)(bv[j].x >> 16);
      h.y = (u16)(bv[j].y & 0xffff); l.y = (u16)(bv[j].y >> 16);
      h.z = (u16)(bv[j].z & 0xffff); l.z = (u16)(bv[j].z >> 16);
      h.w = (u16)(bv[j].w & 0xffff); l.w = (u16)(bv[j].w >> 16);
      *(ushort4*)&Bs_h[base] = h;
      *(ushort4*)&Bs_l[base] = l;
    }
    __syncthreads();

    half8 fa_h[4], fa_l[4], fb_h[4], fb_l[4];
    #pragma unroll
    for(int s = 0; s < 4; s++){
      int ra = (mq + s * 16 + lm) * 40 + lg * 8;
      fa_h[s] = *(const half8*)&As_h[ra];
      fa_l[s] = *(const half8*)&As_l[ra];
      int rb = (nq + s * 16 + lm) * 40 + lg * 8;
      fb_h[s] = *(const half8*)&Bs_h[rb];
      fb_l[s] = *(const half8*)&Bs_l[rb];
    }
    #pragma unroll
    for(int i = 0; i < 4; i++)
      #pragma unroll
      for(int j = 0; j < 4; j++){
        accA[i][j] = __builtin_amdgcn_mfma_f32_16x16x32_f16(fa_h[i], fb_h[j], accA[i][j], 0, 0, 0);
        accB[i][j] = __builtin_amdgcn_mfma_f32_16x16x32_f16(fa_h[i], fb_l[j], accB[i][j], 0, 0, 0);
        accB[i][j] = __builtin_amdgcn_mfma_f32_16x16x32_f16(fa_l[i], fb_h[j], accB[i][j], 0, 0, 0);
      }
  }

  const float inv4096 = 1.f / 4096.f;
  if(MODE == 0 || (MODE == 3 && m0path)){
    int ldy = (MODE == 3) ? HD : N;
    #pragma unroll
    for(int i = 0; i < 4; i++)
      #pragma unroll
      for(int r = 0; r < 4; r++){
        int m = m0 + mq + i * 16 + lg * 4 + r;
        if(m < M){
          #pragma unroll
          for(int j = 0; j < 4; j++){
            int c = n0 + nq + j * 16 + lm;
            Yout[(size_t)m * ldy + c] = accA[i][j][r] + accB[i][j][r] * inv4096;
          }
        }
      }
  } else if(MODE == 1 || MODE == 3){
    int ldh = (MODE == 3) ? HD2 : N;
    #pragma unroll
    for(int i = 0; i < 4; i++)
      #pragma unroll
      for(int r = 0; r < 4; r++){
        int m = m0 + mq + i * 16 + lg * 4 + r;
        if(m < M){
          #pragma unroll
          for(int j = 0; j < 4; j++){
            int c = n0 + nq + j * 16 + lm;
            float v = fmaxf(accA[i][j][r] + accB[i][j][r] * inv4096 + bias[c], 0.f);
            Hout[(size_t)m * ldh + c] = split_pack(v);
          }
        }
      }
  } else {
    #pragma unroll
    for(int i = 0; i < 4; i++)
      #pragma unroll
      for(int r = 0; r < 4; r++){
        float s = 0.f;
        #pragma unroll
        for(int j = 0; j < 4; j++){
          int c = n0 + nq + j * 16 + lm;
          float v = fmaxf(accA[i][j][r] + accB[i][j][r] * inv4096 + bias[c], 0.f);
          s = fmaf(v, m3[c], s);
        }
        s += __shfl_xor(s, 1, 64);
        s += __shfl_xor(s, 2, 64);
        s += __shfl_xor(s, 4, 64);
        s += __shfl_xor(s, 8, 64);
        int m = m0 + mq + i * 16 + lg * 4 + r;
        if(lm == 0 && m < M) atomicAdd(&score[m], s);
      }
  }
}

__global__ void k_final(const float* __restrict__ sc, const float* __restrict__ b3,
                        float* __restrict__ out){
  int i = blockIdx.x * 256 + threadIdx.x;
  if(i < NN){
    float b = 9.f * b3[0];
    out[i] = (sc[i] + b) * (sc[NN + i] + b);
  }
}

// ---------------- launcher ----------------
extern "C" void kernel_launch(void* const* d_in, const int* in_sizes, int n_in,
                              void* d_out, int out_size, void* d_ws, size_t ws_size,
                              hipStream_t stream){
  const int*   a1r = (const int*)d_in[0];
  const int*   a1c = (const int*)d_in[1];
  const float* a1v = (const float*)d_in[2];
  const int*   a2r = (const int*)d_in[3];
  const int*   a2c = (const int*)d_in[4];
  const float* a2v = (const float*)d_in[5];
  const float* w1  = (const float*)d_in[6];
  const float* w[8];
  for(int i = 0; i < 8; i++) w[i] = (const float*)d_in[7 + i];
  const float* m1 = (const float*)d_in[15];
  const float* b1 = (const float*)d_in[16];
  const float* m2 = (const float*)d_in[17];
  const float* b2 = (const float*)d_in[18];
  const float* m3 = (const float*)d_in[19];
  const float* b3 = (const float*)d_in[20];
  float* out = (float*)d_out;

  char* base = (char*)d_ws;
  size_t off = 0;
  auto alloc = [&](size_t bytes) -> char* {
    char* r = base + off;
    off += (bytes + 255) & ~(size_t)255;
    return r;
  };
  int*   c1ptr = (int*)  alloc((size_t)(NN + 1) * 4);
  int*   c2ptr = (int*)  alloc((size_t)(NN + 1) * 4);
  uint2* ecv1  = (uint2*)alloc((size_t)NE * 8);
  uint2* ecv2  = (uint2*)alloc((size_t)NE * 8);
  int*   cursor= (int*)  alloc((size_t)2 * NBK * 4);
  int*   bbase = (int*)  alloc((size_t)2 * NBK * 4);
  float* sc    = (float*)alloc((size_t)2 * NN * 4);
  u32*   wtpk[8];
  for(int i = 0; i < 8; i++) wtpk[i] = (u32*)alloc((size_t)HD * HD * 4);
  u32*   m1tpk = (u32*)alloc((size_t)HD2 * HD * 4);
  u32*   m2tpk = (u32*)alloc((size_t)HD2 * HD2 * 4);
  u32*   xpk   = (u32*)alloc((size_t)NN * HD * 4);
  u32*   h1pk  = (u32*)alloc((size_t)NN * HD2 * 4);
  // fused01 tier needs dedicated y (fp32 [NN][HD]); else alias h1pk and run r6 schedule
  size_t need_ded = off + (((size_t)NN * HD * 4 + 255) & ~(size_t)255);
  bool ded_y = (ws_size >= need_ded);
  float* y = ded_y ? (float*)alloc((size_t)NN * HD * 4) : (float*)h1pk;

  // binned-scatter staging aliases h1pk (dead during CSR build): 50.3MB < 102.4MB
  // layout: sv1 [0, SZ*8) | sr1 [SZ*8, SZ*12) | sv2 [SZ*12, SZ*20) | sr2 [SZ*20, SZ*24)
  const size_t SZ = (size_t)NBK * CAP;
  char* hb = (char*)h1pk;
  uint2* sv1 = (uint2*)hb;
  u32*   sr1 = (u32*)(hb + SZ * 8);
  uint2* sv2 = (uint2*)(hb + SZ * 12);
  u32*   sr2 = (u32*)(hb + SZ * 20);

  // ---- bucketized CSR build (both adjacencies; no global per-row histogram) ----
  hipLaunchKernelGGL(k_init_bcap, dim3(cdiv(2 * NBK, 256)), dim3(256), 0, stream, cursor);
  hipLaunchKernelGGL(k_binscatter, dim3(cdiv(NE, CH), 2), dim3(256), 0, stream,
                     a1r, a1c, a1v, a2r, a2c, a2v, cursor, sr1, sv1, sr2, sv2);
  hipLaunchKernelGGL(k_bucket_scan, dim3(2), dim3(256), 0, stream, cursor, bbase, c1ptr, c2ptr);
  hipLaunchKernelGGL(k_bucket_place, dim3(NBK, 2), dim3(256), 0, stream,
                     cursor, bbase, sr1, sv1, sr2, sv2, c1ptr, c2ptr, ecv1, ecv2);

  auto splitw = [&](const float* W, u32* o, int K, int N){
    int total = K * N;
    hipLaunchKernelGGL(k_splitw, dim3(cdiv(total, 256)), dim3(256), 0, stream, W, o, K, N, total);
  };
  for(int i = 0; i < 8; i++) splitw(w[i], wtpk[i], HD, HD);
  splitw(m1, m1tpk, HD, HD2);
  splitw(m2, m2tpk, HD2, HD2);
  hipLaunchKernelGGL(k_zero_f, dim3(cdiv(2 * NN, 256)), dim3(256), 0, stream, sc, 2 * NN);

  const int NRT = cdiv(NN, 128);          // 782 row tiles
  const int GP  = cdiv(NRT, 8) * 8;       // 784 padded rows
  auto mode1 = [&](){
    hipLaunchKernelGGL((k_mfma_gemm<1>), dim3(GP * 2), dim3(256), 0, stream,
                       xpk, m1tpk, (const u32*)nullptr, b1, (float*)nullptr, h1pk,
                       (const float*)nullptr, (float*)nullptr, NN, HD, HD2);
  };
  auto mode2 = [&](float* score){
    hipLaunchKernelGGL((k_mfma_gemm<2>), dim3(GP * 2), dim3(256), 0, stream,
                       h1pk, m2tpk, (const u32*)nullptr, b2, (float*)nullptr, (u32*)nullptr,
                       m3, score, NN, HD2, HD2);
  };
  auto gemm0 = [&](int i){
    hipLaunchKernelGGL((k_mfma_gemm<0>), dim3(GP * 1), dim3(256), 0, stream,
                       xpk, wtpk[i], (const u32*)nullptr, (const float*)nullptr, y, (u32*)nullptr,
                       (const float*)nullptr, (float*)nullptr, NN, HD, HD);
  };
  auto fused01 = [&](int i){
    hipLaunchKernelGGL((k_mfma_gemm<3>), dim3(GP * 3), dim3(256), 0, stream,
                       xpk, wtpk[i], m1tpk, b1, y, h1pk,
                       (const float*)nullptr, (float*)nullptr, NN, HD, 0);
  };

  for(int b = 0; b < 2; b++){
    const int* rp = b ? c2ptr : c1ptr;
    const uint2* ecv = b ? ecv2 : ecv1;
    float* score = sc + (size_t)b * NN;
    hipLaunchKernelGGL((k_spmm<true>), dim3(cdiv(NN, 4)), dim3(256), 0, stream,
                       rp, ecv, w1, xpk);
    if(ded_y){
      // spmm; 8x [fused01(h1,y); mode2; spmm]; mode1; mode2
      for(int i = 0; i < 8; i++){
        fused01(i);
        mode2(score);
        if(i < 7)
          hipLaunchKernelGGL((k_spmm<true>),  dim3(cdiv(NN, 4)), dim3(256), 0, stream,
                             rp, ecv, y, xpk);
        else
          hipLaunchKernelGGL((k_spmm<false>), dim3(cdiv(NN, 4)), dim3(256), 0, stream,
                             rp, ecv, y, xpk);
      }
      mode1();
      mode2(score);
    } else {
      // r6-proven serial order (y aliases h1pk)
      mode1();
      mode2(score);
      for(int i = 0; i < 8; i++){
        gemm0(i);
        if(i < 7)
          hipLaunchKernelGGL((k_spmm<true>),  dim3(cdiv(NN, 4)), dim3(256), 0, stream,
                             rp, ecv, y, xpk);
        else
          hipLaunchKernelGGL((k_spmm<false>), dim3(cdiv(NN, 4)), dim3(256), 0, stream,
                             rp, ecv, y, xpk);
        mode1();
        mode2(score);
      }
    }
  }

  hipLaunchKernelGGL(k_final, dim3(cdiv(NN, 256)), dim3(256), 0, stream, sc, b3, out);
}